// Round 2
// baseline (1354.656 us; speedup 1.0000x reference)
//
#include <hip/hip_runtime.h>

// Problem constants (fixed by the reference: B=4, MAX_LEN=4096, H=32, D=128, Q_LEN=1)
constexpr long long N_ELEM  = 4LL * 4096 * 32 * 128; // 67,108,864 per K or V tensor
constexpr long long N_ROWS  = 4LL * 4096 * 32;       // 524,288 rows of D=128
constexpr long long MASK_N  = 4LL * 4096;            // 16,384
constexpr long long SCALE_N = N_ROWS;                // 524,288

// d_out float32 layout (flat, return order):
//   [0, N)                  key_out
//   [N, 2N)                 value_out
//   [2N, 2N+MASK)           attn_mask_out (bool as 0.0/1.0)
//   [2N+MASK, 3N+MASK)      key_q (int8 value as float)
//   [3N+MASK, +SCALE)       key_scale
//   [.., +N)                value_q
//   [.., +SCALE)            value_scale

typedef float vf4 __attribute__((ext_vector_type(4)));

// Persistent blocked workers: 2048 blocks x 8 half-waves = 16,384 workers.
// Each worker owns 16 CONSECUTIVE quads (64 consecutive rows) -> 32 KB
// sequential per address stream, register-double-buffered. Long-lived
// sequential streams instead of one-shot 2 KB bursts.
constexpr int QUADS_PER_WORKER = 16;
constexpr int NUM_BLOCKS = 2048;   // 2048*8*16 quads = 262,144 = 1,048,576 rows

__global__ __launch_bounds__(256) void kv_update_quant_kernel(
    const float* __restrict__ cached_key,
    const float* __restrict__ cached_value,
    const float* __restrict__ key_new,     // (B,1,H,D)
    const float* __restrict__ value_new,   // (B,1,H,D)
    const int*   __restrict__ cache_index,
    float* __restrict__ out)
{
    const int cur  = cache_index[0];
    const int hw   = threadIdx.x >> 5;   // half-wave id 0..7
    const int lane = threadIdx.x & 31;

    const long long w  = (long long)blockIdx.x * 8 + hw;       // worker id
    const long long q0 = w * QUADS_PER_WORKER;                 // first quad (4-row unit)

    // A 16-quad chunk never straddles the key/value boundary (131072 % 16 == 0),
    // nor a batch boundary (32768 quads per b) -> hoist all per-tensor bases.
    const bool isv = (q0 << 2) >= N_ROWS;
    const long long rbase = (q0 << 2) - (isv ? N_ROWS : 0);    // first in-tensor row

    const float* cached = isv ? cached_value : cached_key;
    const float* knew   = isv ? value_new   : key_new;

    float* out_base = out + (isv ? N_ELEM : 0);
    float* q_base   = out + 2 * N_ELEM + MASK_N + (isv ? (N_ELEM + SCALE_N) : 0);
    float* s_base   = out + 3 * N_ELEM + MASK_N + (isv ? (N_ELEM + SCALE_N) : 0);

    // dynamic_update_slice: rows at s == cache_index come from the new K/V.
    auto src_for = [&](long long r0) -> const float* {
        const int s = (int)((r0 >> 5) & 4095);
        if (s == cur) {
            const long long b = r0 >> 17;
            const int h0 = (int)(r0 & 31);
            return knew + (((b << 5) + (long long)h0) << 7) + (lane << 2);
        }
        return cached + (r0 << 7) + (lane << 2);
    };

    // Prologue: load quad 0.
    vf4 v[4];
    {
        const float* src = src_for(rbase);
        #pragma unroll
        for (int j = 0; j < 4; ++j)
            v[j] = __builtin_nontemporal_load(reinterpret_cast<const vf4*>(src + (j << 7)));
    }

    for (int i = 0; i < QUADS_PER_WORKER; ++i) {
        const long long r0 = rbase + ((long long)i << 2);

        // Issue next quad's loads before this quad's stores (reg double-buffer).
        vf4 nv[4];
        if (i + 1 < QUADS_PER_WORKER) {
            const float* nsrc = src_for(r0 + 4);
            #pragma unroll
            for (int j = 0; j < 4; ++j)
                nv[j] = __builtin_nontemporal_load(reinterpret_cast<const vf4*>(nsrc + (j << 7)));
        }

        // Per-row max|x| over the 128-row: 4 local, then 5-step xor-shuffle across
        // the half-wave (masks <= 16 keep the two 32-lane halves independent).
        float sc[4];
        #pragma unroll
        for (int j = 0; j < 4; ++j) {
            float m = fmaxf(fmaxf(fabsf(v[j].x), fabsf(v[j].y)),
                            fmaxf(fabsf(v[j].z), fabsf(v[j].w)));
            #pragma unroll
            for (int off = 16; off >= 1; off >>= 1)
                m = fmaxf(m, __shfl_xor(m, off));
            // IEEE f32 div + rintf (round-half-even) matches jnp round/div bitwise.
            sc[j] = fmaxf(m / 127.0f, 1e-8f);
        }

        float* out_p = out_base + (r0 << 7) + (lane << 2);
        float* q_p   = q_base   + (r0 << 7) + (lane << 2);

        #pragma unroll
        for (int j = 0; j < 4; ++j) {
            __builtin_nontemporal_store(v[j], reinterpret_cast<vf4*>(out_p + (j << 7)));
            vf4 q;
            q.x = fminf(fmaxf(rintf(v[j].x / sc[j]), -128.0f), 127.0f);
            q.y = fminf(fmaxf(rintf(v[j].y / sc[j]), -128.0f), 127.0f);
            q.z = fminf(fmaxf(rintf(v[j].z / sc[j]), -128.0f), 127.0f);
            q.w = fminf(fmaxf(rintf(v[j].w / sc[j]), -128.0f), 127.0f);
            __builtin_nontemporal_store(q, reinterpret_cast<vf4*>(q_p + (j << 7)));
        }

        // 4 consecutive per-row scales -> one 16 B nt store from lane 0.
        if (lane == 0) {
            vf4 sv;
            sv.x = sc[0]; sv.y = sc[1]; sv.z = sc[2]; sv.w = sc[3];
            __builtin_nontemporal_store(sv, reinterpret_cast<vf4*>(s_base + r0));
        }

        #pragma unroll
        for (int j = 0; j < 4; ++j) v[j] = nv[j];   // dead on last iter, harmless
    }
}

__global__ __launch_bounds__(256) void mask_kernel(
    const int* __restrict__ attention_mask,   // bool input, harness passes integer
    const int* __restrict__ cache_index,
    float* __restrict__ out_mask)             // 16,384 floats at out + 2N
{
    const int i = blockIdx.x * 256 + threadIdx.x;
    if (i < (int)MASK_N) {
        const int pos = i & 4095;
        const bool pad = pos < (cache_index[0] + 1);   // arange(max_len) < cur + num_updated
        const bool am  = attention_mask[i] != 0;
        out_mask[i] = (pad && am) ? 1.0f : 0.0f;
    }
}

extern "C" void kernel_launch(void* const* d_in, const int* in_sizes, int n_in,
                              void* d_out, int out_size, void* d_ws, size_t ws_size,
                              hipStream_t stream) {
    const float* cached_key   = (const float*)d_in[0];
    const float* cached_value = (const float*)d_in[1];
    const float* key_new      = (const float*)d_in[2];
    const float* value_new    = (const float*)d_in[3];
    const int*   attn_mask    = (const int*)d_in[4];
    const int*   cache_index  = (const int*)d_in[5];
    float* out = (float*)d_out;

    kv_update_quant_kernel<<<NUM_BLOCKS, 256, 0, stream>>>(
        cached_key, cached_value, key_new, value_new, cache_index, out);

    mask_kernel<<<(int)(MASK_N / 256), 256, 0, stream>>>(
        attn_mask, cache_index, out + 2 * N_ELEM);
}